// Round 6
// baseline (645.643 us; speedup 1.0000x reference)
//
#include <hip/hip_runtime.h>
#include <math.h>

#define NL 16
#define DD 128

typedef __attribute__((ext_vector_type(8))) short short8;
typedef __attribute__((ext_vector_type(4))) float floatx4;

union U8 { short8 v; unsigned short s[8]; };

__device__ __forceinline__ unsigned short f2bf(float x) {
  union { float f; unsigned u; } v; v.f = x; return (unsigned short)(v.u >> 16);
}
__device__ __forceinline__ float bf2f(unsigned short s) {
  union { unsigned u; float f; } v; v.u = ((unsigned)s) << 16; return v.f;
}

// ---------------- segment table ----------------
__global__ void seg_kernel(const int* __restrict__ db, int nd,
                           const int* __restrict__ eb, int ne,
                           int* __restrict__ seg) {
  const int* arr = (blockIdx.x == 0) ? db : eb;
  int n = (blockIdx.x == 0) ? nd : ne;
  int* start = seg + blockIdx.x * 1024;
  int* cnt = start + 512;
  int b = threadIdx.x;
  if (b < 512) {
    int lo = 0, hi = n;
    while (lo < hi) { int mid = (lo + hi) >> 1; if (arr[mid] < b) lo = mid + 1; else hi = mid; }
    int s = lo;
    lo = s; hi = n;
    while (lo < hi) { int mid = (lo + hi) >> 1; if (arr[mid] < b + 1) lo = mid + 1; else hi = mid; }
    start[b] = s; cnt[b] = lo - s;
  }
}

// ---------------- lat init (float4) ----------------
__global__ void init_lat_kernel(const float* __restrict__ latents, float* __restrict__ lat) {
  int i = blockIdx.x * blockDim.x + threadIdx.x;
  ((float4*)lat)[i] = ((const float4*)latents)[i & 511];
}

// convert post weights to bf16, per-layer contiguous blocks
__global__ void cvtw_kernel(const float* __restrict__ mw_d, const float* __restrict__ ow_d,
                            const float* __restrict__ mw_e, const float* __restrict__ ow_e,
                            const float* __restrict__ w1, const float* __restrict__ w2,
                            unsigned short* __restrict__ Wbf) {
  int l = blockIdx.x >> 7, blk = blockIdx.x & 127;
  int idx = blk * 1024 + threadIdx.x * 4;
  const float* src; int off;
  if (idx < 16384)      { src = mw_d + (size_t)l * 49152 + 32768; off = idx; }
  else if (idx < 32768) { src = ow_d + (size_t)l * 16384; off = idx - 16384; }
  else if (idx < 49152) { src = mw_e + (size_t)l * 49152 + 32768; off = idx - 32768; }
  else if (idx < 65536) { src = ow_e + (size_t)l * 16384; off = idx - 49152; }
  else if (idx < 98304) { src = w1 + (size_t)l * 32768; off = idx - 65536; }
  else                  { src = w2 + (size_t)l * 32768; off = idx - 98304; }
  float4 v = *(const float4*)(src + off);
  ushort4 o = { f2bf(v.x), f2bf(v.y), f2bf(v.z), f2bf(v.w) };
  *(ushort4*)(Wbf + (size_t)l * 131072 + idx) = o;
}

// convert head w1 (128x2048) to bf16
__global__ void cvth_kernel(const float* __restrict__ w1, unsigned short* __restrict__ dst) {
  int i = blockIdx.x * blockDim.x + threadIdx.x;  // 65536 float4s
  float4 v = ((const float4*)w1)[i];
  ushort4 o = { f2bf(v.x), f2bf(v.y), f2bf(v.z), f2bf(v.w) };
  ((ushort4*)dst)[i] = o;
}

// ---------------- fold: Wqf = mwq @ wq (scaled), fp32 ----------------
__global__ __launch_bounds__(256) void fold_kernel(
    const float* __restrict__ wq_d, const float* __restrict__ bq_d,
    const float* __restrict__ wq_e, const float* __restrict__ bq_e,
    const float* __restrict__ mw_d, const float* __restrict__ mb_d,
    const float* __restrict__ mw_e, const float* __restrict__ mb_e,
    float* __restrict__ Wqf, float* __restrict__ bqf) {
  __shared__ __align__(16) float sMW[2048];
  const int pb = blockIdx.x >> 3, rg = blockIdx.x & 7;
  const int l = pb >> 1, p = pb & 1;
  const float* wq = (p == 0 ? wq_d : wq_e) + (size_t)l * 16384;
  const float* bq = (p == 0 ? bq_d : bq_e) + l * 128;
  const float* mw = (p == 0 ? mw_d : mw_e) + (size_t)l * 49152;
  const float* mb = (p == 0 ? mb_d : mb_e) + l * 384;
  const float scale = 0.17677669529663687f;
  const int tid = threadIdx.x;
  {
    const float4* src = (const float4*)(mw + rg * 2048);
    ((float4*)sMW)[tid] = src[tid];
    ((float4*)sMW)[tid + 256] = src[tid + 256];
  }
  __syncthreads();
  const int j = tid & 127, ih = tid >> 7;
  float acc[8];
#pragma unroll
  for (int r = 0; r < 8; ++r) acc[r] = 0.f;
#pragma unroll 4
  for (int k = 0; k < 128; ++k) {
    float wv = wq[k * 128 + j];
#pragma unroll
    for (int r = 0; r < 8; ++r) acc[r] += sMW[(ih * 8 + r) * 128 + k] * wv;
  }
  float* W = Wqf + (size_t)pb * 16384 + (rg * 16 + ih * 8) * 128 + j;
#pragma unroll
  for (int r = 0; r < 8; ++r) W[r * 128] = acc[r] * scale;
  if (rg == 0 && tid < 128) {
    float s = 0.f;
    const float* mr = mw + tid * 128;
    for (int k = 0; k < 128; ++k) s += mr[k] * bq[k];
    bqf[pb * 128 + tid] = (s + mb[tid]) * scale;
  }
}

// ---------------- wt: pre-folded q~ weights in MFMA B-frag order ----------------
__global__ __launch_bounds__(256) void wt_kernel(
    const float* __restrict__ Wqf, const float* __restrict__ bqf,
    const float* __restrict__ mw_d, const float* __restrict__ mw_e,
    unsigned short* __restrict__ WtB, float* __restrict__ bt) {
  const int l = blockIdx.x >> 3, p = (blockIdx.x >> 2) & 1, h = blockIdx.x & 3;
  const float* wqf = Wqf + (size_t)(l * 2 + p) * 16384 + (h * 32) * 128;
  const float* wk  = (p == 0 ? mw_d : mw_e) + (size_t)l * 49152 + 16384 + (h * 32) * 128;
  const float* bqv = bqf + (l * 2 + p) * 128 + h * 32;
  __shared__ __align__(16) float sWq[4096];
  __shared__ __align__(16) float sWk[4096];
  __shared__ float sBq[32];
  const int tid = threadIdx.x;
  for (int i = tid; i < 1024; i += 256) {
    ((float4*)sWq)[i] = ((const float4*)wqf)[i];
    ((float4*)sWk)[i] = ((const float4*)wk)[i];
  }
  if (tid < 32) sBq[tid] = bqv[tid];
  __syncthreads();
  const int d = tid & 127, kh = tid >> 7;
  const int n = p * 512 + h * 128 + d;
  const int tn = n >> 4, m = n & 15;
  unsigned short* outl = WtB + (size_t)l * 131072;
#pragma unroll
  for (int kc = 0; kc < 4; ++kc) {
    int k0 = kh * 64 + kc * 16;
    float acc[16];
#pragma unroll
    for (int kk = 0; kk < 16; ++kk) acc[kk] = 0.f;
    for (int j = 0; j < 32; ++j) {
      float wkd = sWk[j * 128 + d];
#pragma unroll
      for (int kk = 0; kk < 16; ++kk) acc[kk] += sWq[j * 128 + k0 + kk] * wkd;
    }
#pragma unroll
    for (int kk = 0; kk < 16; ++kk) {
      int k = k0 + kk;
      int c = k >> 5, quad = (k >> 3) & 3, j8 = k & 7;
      int lane = quad * 16 + m;
      outl[(((size_t)tn * 4 + c) * 64 + lane) * 8 + j8] = f2bf(acc[kk]);
    }
  }
  if (kh == 0) {
    float a = 0.f;
    for (int j = 0; j < 32; ++j) a += sBq[j] * sWk[j * 128 + d];
    bt[l * 1024 + n] = a;
  }
}

// ---------------- standalone Q~ (layer 0 only, grid=1: lat identical across batches) ----------------
__global__ __launch_bounds__(256) void qtilde_kernel(
    const float* __restrict__ lat,
    const float* __restrict__ lng, const float* __restrict__ lnb,
    const unsigned short* __restrict__ WtBl, const float* __restrict__ btl,
    unsigned short* __restrict__ Qt) {
  __shared__ __align__(16) unsigned short sNL[16 * 136];
  const int tid = threadIdx.x;
  const int b = blockIdx.x;
  {
    int q = tid >> 4, li = tid & 15, d0 = li * 8;
    const float* xr = lat + ((size_t)b * NL + q) * DD + d0;
    float x[8];
    *(float4*)(x) = *(const float4*)(xr);
    *(float4*)(x + 4) = *(const float4*)(xr + 4);
    float s1 = 0.f, s2 = 0.f;
#pragma unroll
    for (int j = 0; j < 8; ++j) { s1 += x[j]; s2 += x[j] * x[j]; }
#pragma unroll
    for (int o = 1; o < 16; o <<= 1) { s1 += __shfl_xor(s1, o); s2 += __shfl_xor(s2, o); }
    float mean = s1 * (1.f / 128.f);
    float var = s2 * (1.f / 128.f) - mean * mean;
    float rstd = rsqrtf(var + 1e-5f);
    float y[8];
#pragma unroll
    for (int j = 0; j < 8; ++j)
      y[j] = (x[j] - mean) * rstd * lng[d0 + j] + lnb[d0 + j];
    ushort4 o0 = { f2bf(y[0]), f2bf(y[1]), f2bf(y[2]), f2bf(y[3]) };
    ushort4 o1 = { f2bf(y[4]), f2bf(y[5]), f2bf(y[6]), f2bf(y[7]) };
    *(ushort4*)(sNL + q * 136 + d0) = o0;
    *(ushort4*)(sNL + q * 136 + d0 + 4) = o1;
  }
  __syncthreads();
  const int lane = tid & 63, w = tid >> 6, m = lane & 15, quad = lane >> 4;
  short8 aF[4];
  {
    const unsigned short* arow = sNL + m * 136 + quad * 8;
#pragma unroll
    for (int c = 0; c < 4; ++c) aF[c] = *(const short8*)(arow + c * 32);
  }
  unsigned short* qtb = Qt + (size_t)b * 16384;
#pragma unroll
  for (int t = 0; t < 16; ++t) {
    int tn = w * 16 + t;
    floatx4 acc = (floatx4){0.f, 0.f, 0.f, 0.f};
#pragma unroll
    for (int c = 0; c < 4; ++c) {
      short8 bF = *(const short8*)(WtBl + (((size_t)tn * 4 + c) * 64 + lane) * 8);
      acc = __builtin_amdgcn_mfma_f32_16x16x32_bf16(aF[c], bF, acc, 0, 0, 0);
    }
    int n = tn * 16 + m;
    float bb = btl[n];
    int p = n >> 9, h = (n >> 7) & 3, d = n & 127;
    unsigned short* op = qtb + (p * 64 + h * 16) * 128 + d;
#pragma unroll
    for (int r = 0; r < 4; ++r) op[(quad * 4 + r) * 128] = f2bf(acc[r] + bb);
  }
}

// ---------------- fused MFMA flash attention; cvt=1: fp32 in + bf16 side-write ----------------
__global__ __launch_bounds__(256, 4) void attn3_kernel(
    const float* __restrict__ Kd32, const float* __restrict__ Vd32,
    const float* __restrict__ Ke32, const float* __restrict__ Ve32,
    unsigned short* __restrict__ Kd, unsigned short* __restrict__ Vd,
    unsigned short* __restrict__ Ke, unsigned short* __restrict__ Ve,
    const int* __restrict__ seg,
    const unsigned short* __restrict__ Qt, int qstride, int cvt,
    unsigned short* __restrict__ part_d, float* __restrict__ l_d,
    unsigned short* __restrict__ part_e, float* __restrict__ l_e) {
  __shared__ __align__(16) unsigned short sK[32 * 136];
  __shared__ __align__(16) unsigned short sV[128 * 40];
  __shared__ __align__(16) unsigned short sP[64 * 40];
  const int tid = threadIdx.x;
  const int bi = blockIdx.x;

  const float* Kp32; const float* Vp32;
  unsigned short* KpB; unsigned short* VpB;
  const unsigned short* qt;
  unsigned short* part; float* lpart;
  int len, st;
  if (bi < 2048) {
    int b = bi >> 2, sp = bi & 3;
    int n = seg[1536 + b]; if (n > 512) n = 512;
    int chunk = (n + 3) >> 2;
    int begin = sp * chunk;
    len = n - begin; if (len > chunk) len = chunk; if (len < 0) len = 0;
    st = seg[1024 + b] + begin;
    Kp32 = Ke32; Vp32 = Ve32; KpB = Ke; VpB = Ve;
    qt = Qt + (size_t)b * qstride + 8192;
    part = part_e + (size_t)bi * 8192;
    lpart = l_e + (size_t)bi * 64;
  } else {
    int b = bi - 2048;
    int n = seg[512 + b]; if (n > 128) n = 128;
    len = n;
    st = seg[b];
    Kp32 = Kd32; Vp32 = Vd32; KpB = Kd; VpB = Vd;
    qt = Qt + (size_t)b * qstride;
    part = part_d + (size_t)b * 8192;
    lpart = l_d + (size_t)b * 64;
  }

  const int lane = tid & 63;
  const int w = tid >> 6;
  const int m = lane & 15;
  const int quad = lane >> 4;

  short8 qA[4];
  {
    const unsigned short* qrow = qt + (size_t)(w * 16 + m) * 128 + quad * 8;
#pragma unroll
    for (int c = 0; c < 4; ++c) qA[c] = *(const short8*)(qrow + c * 32);
  }

  floatx4 oA[8];
#pragma unroll
  for (int i = 0; i < 8; ++i) oA[i] = (floatx4){0.f, 0.f, 0.f, 0.f};
  float lp[4] = {0.f, 0.f, 0.f, 0.f};

  short8 rK[2], rV[2];
  const short8 z8 = {0, 0, 0, 0, 0, 0, 0, 0};
  // both K and V use dim-fastest mapping: tok=f>>4, d8=f&15 (coalesced)
  auto load_tile = [&](int t0) {
    int nv = len - t0; if (nv > 32) nv = 32;
    if (cvt) {
#pragma unroll
      for (int it = 0; it < 2; ++it) {
        int f = tid + it * 256;
        int tok = f >> 4, d8 = f & 15;
        if (tok < nv) {
          size_t g = (size_t)(st + t0 + tok) * 128 + d8 * 8;
          const float* s = Kp32 + g;
          float4 a = *(const float4*)s, c = *(const float4*)(s + 4);
          U8 u;
          u.s[0]=f2bf(a.x); u.s[1]=f2bf(a.y); u.s[2]=f2bf(a.z); u.s[3]=f2bf(a.w);
          u.s[4]=f2bf(c.x); u.s[5]=f2bf(c.y); u.s[6]=f2bf(c.z); u.s[7]=f2bf(c.w);
          rK[it] = u.v;
          *(short8*)(KpB + g) = u.v;
        } else rK[it] = z8;
      }
#pragma unroll
      for (int it = 0; it < 2; ++it) {
        int f = tid + it * 256;
        int tok = f >> 4, d8 = f & 15;
        if (tok < nv) {
          size_t g = (size_t)(st + t0 + tok) * 128 + d8 * 8;
          const float* s = Vp32 + g;
          float4 a = *(const float4*)s, c = *(const float4*)(s + 4);
          U8 u;
          u.s[0]=f2bf(a.x); u.s[1]=f2bf(a.y); u.s[2]=f2bf(a.z); u.s[3]=f2bf(a.w);
          u.s[4]=f2bf(c.x); u.s[5]=f2bf(c.y); u.s[6]=f2bf(c.z); u.s[7]=f2bf(c.w);
          rV[it] = u.v;
          *(short8*)(VpB + g) = u.v;
        } else rV[it] = z8;
      }
    } else {
#pragma unroll
      for (int it = 0; it < 2; ++it) {
        int f = tid + it * 256;
        int tok = f >> 4, d8 = f & 15;
        size_t g = (size_t)(st + t0 + tok) * 128 + d8 * 8;
        rK[it] = (tok < nv) ? *(const short8*)(KpB + g) : z8;
        rV[it] = (tok < nv) ? *(const short8*)(VpB + g) : z8;
      }
    }
  };
  auto store_tile = [&]() {
#pragma unroll
    for (int it = 0; it < 2; ++it) {
      int f = tid + it * 256;
      int tok = f >> 4, d8 = f & 15;
      *(short8*)(sK + tok * 136 + d8 * 8) = rK[it];
      U8 u; u.v = rV[it];
#pragma unroll
      for (int i = 0; i < 8; ++i) {
        int j = (i + d8) & 7;  // rotated to spread banks
        sV[(d8 * 8 + j) * 40 + tok] = u.s[j];
      }
    }
  };

  if (len > 0) load_tile(0);
  for (int t0 = 0; t0 < len; t0 += 32) {
    __syncthreads();
    store_tile();
    __syncthreads();
    if (t0 + 32 < len) load_tile(t0 + 32);
    int nv = len - t0; if (nv > 32) nv = 32;
    floatx4 sS[2];
    sS[0] = (floatx4){0.f, 0.f, 0.f, 0.f};
    sS[1] = (floatx4){0.f, 0.f, 0.f, 0.f};
#pragma unroll
    for (int g = 0; g < 2; ++g)
#pragma unroll
      for (int c = 0; c < 4; ++c) {
        short8 kB = *(const short8*)(sK + (g * 16 + m) * 136 + c * 32 + quad * 8);
        sS[g] = __builtin_amdgcn_mfma_f32_16x16x32_bf16(qA[c], kB, sS[g], 0, 0, 0);
      }
#pragma unroll
    for (int g = 0; g < 2; ++g) {
      bool valid = (g * 16 + m) < nv;
#pragma unroll
      for (int r = 0; r < 4; ++r) {
        float p = valid ? __expf(sS[g][r]) : 0.f;
        lp[r] += p;
        sP[(w * 16 + quad * 4 + r) * 40 + g * 16 + m] = f2bf(p);
      }
    }
    short8 pA = *(const short8*)(sP + (w * 16 + m) * 40 + quad * 8);
#pragma unroll
    for (int dg = 0; dg < 8; ++dg) {
      short8 vB = *(const short8*)(sV + (dg * 16 + m) * 40 + quad * 8);
      oA[dg] = __builtin_amdgcn_mfma_f32_16x16x32_bf16(pA, vB, oA[dg], 0, 0, 0);
    }
  }

#pragma unroll
  for (int r = 0; r < 4; ++r) {
    float v = lp[r];
    v += __shfl_xor(v, 1); v += __shfl_xor(v, 2);
    v += __shfl_xor(v, 4); v += __shfl_xor(v, 8);
    lp[r] = v;
  }
  if (m == 0) {
#pragma unroll
    for (int r = 0; r < 4; ++r)
      lpart[w * 16 + quad * 4 + r] = lp[r];
  }
#pragma unroll
  for (int dg = 0; dg < 8; ++dg)
#pragma unroll
    for (int r = 0; r < 4; ++r)
      part[(w * 16 + quad * 4 + r) * 128 + dg * 16 + m] = f2bf(oA[dg][r]);
}

// ---------------- MFMA post + fused next-layer Q~ ----------------
__global__ __launch_bounds__(256) void post_kernel(
    const unsigned short* __restrict__ pd, const float* __restrict__ ldv,
    const unsigned short* __restrict__ pe, const float* __restrict__ lev,
    const unsigned short* __restrict__ Wl,
    const float* __restrict__ bv_d, const float* __restrict__ ob_d,
    const float* __restrict__ bv_e, const float* __restrict__ ob_e,
    const float* __restrict__ ln2g, const float* __restrict__ ln2b,
    const float* __restrict__ b1, const float* __restrict__ b2,
    float* __restrict__ lat,
    const float* __restrict__ lng1, const float* __restrict__ lnb1,
    const unsigned short* __restrict__ WtB_next, const float* __restrict__ bt_next,
    unsigned short* __restrict__ Qt) {
  const unsigned short* wv_d = Wl;
  const unsigned short* ow_d = Wl + 16384;
  const unsigned short* wv_e = Wl + 32768;
  const unsigned short* ow_e = Wl + 49152;
  const unsigned short* w1   = Wl + 65536;
  const unsigned short* w2   = Wl + 98304;

  __shared__ __align__(16) unsigned short sX[64 * 136];
  __shared__ __align__(16) unsigned short sVH[16 * 136];
  __shared__ __align__(16) unsigned short sF[16 * 264];
  __shared__ __align__(16) float sAcc[16 * 132];
  __shared__ float sLd[64], sLe[64];

  const int tid = threadIdx.x;
  const int b = blockIdx.x;
  const int lane = tid & 63;
  const int w = tid >> 6;
  const int m = lane & 15;
  const int quad = lane >> 4;

  if (tid < 64) {
    float v = ldv[(size_t)b * 64 + tid];
    sLd[tid] = (v > 0.f) ? 1.f / v : 0.f;
  } else if (tid < 128) {
    int r = tid - 64;
    float v = lev[((size_t)b * 4 + 0) * 64 + r] + lev[((size_t)b * 4 + 1) * 64 + r]
            + lev[((size_t)b * 4 + 2) * 64 + r] + lev[((size_t)b * 4 + 3) * 64 + r];
    sLe[r] = (v > 0.f) ? 1.f / v : 0.f;
  }
  __syncthreads();
  {
    const ushort4* src = (const ushort4*)(pd + (size_t)b * 8192);
#pragma unroll
    for (int it = 0; it < 8; ++it) {
      int f = tid + it * 256;
      int row = f >> 5, d = (f & 31) * 4;
      ushort4 u = src[f];
      float sc = sLd[row];
      ushort4 o = { f2bf(bf2f(u.x) * sc), f2bf(bf2f(u.y) * sc),
                    f2bf(bf2f(u.z) * sc), f2bf(bf2f(u.w) * sc) };
      *(ushort4*)(sX + row * 136 + d) = o;
    }
  }
  __syncthreads();
  {
    short8 aF[4];
    const unsigned short* arow = sX + (w * 16 + m) * 136 + quad * 8;
#pragma unroll
    for (int c = 0; c < 4; ++c) aF[c] = *(const short8*)(arow + c * 32);
#pragma unroll
    for (int t = 0; t < 2; ++t) {
      int n = w * 32 + t * 16 + m;
      floatx4 acc = (floatx4){0.f, 0.f, 0.f, 0.f};
      const unsigned short* brow = wv_d + n * 128 + quad * 8;
#pragma unroll
      for (int c = 0; c < 4; ++c)
        acc = __builtin_amdgcn_mfma_f32_16x16x32_bf16(aF[c], *(const short8*)(brow + c * 32), acc, 0, 0, 0);
      float bb = bv_d[n];
#pragma unroll
      for (int r = 0; r < 4; ++r) sVH[(quad * 4 + r) * 136 + n] = f2bf(acc[r] + bb);
    }
  }
  __syncthreads();
  {
    short8 aF[4];
    const unsigned short* arow = sVH + m * 136 + quad * 8;
#pragma unroll
    for (int c = 0; c < 4; ++c) aF[c] = *(const short8*)(arow + c * 32);
#pragma unroll
    for (int t = 0; t < 2; ++t) {
      int n = w * 32 + t * 16 + m;
      floatx4 acc = (floatx4){0.f, 0.f, 0.f, 0.f};
      const unsigned short* brow = ow_d + n * 128 + quad * 8;
#pragma unroll
      for (int c = 0; c < 4; ++c)
        acc = __builtin_amdgcn_mfma_f32_16x16x32_bf16(aF[c], *(const short8*)(brow + c * 32), acc, 0, 0, 0);
      float bb = ob_d[n];
#pragma unroll
      for (int r = 0; r < 4; ++r) {
        int q = quad * 4 + r;
        sAcc[q * 132 + n] = lat[(size_t)b * 2048 + q * 128 + n] + acc[r] + bb;
      }
    }
  }
  __syncthreads();
  {
    const ushort4* s0 = (const ushort4*)(pe + ((size_t)b * 4 + 0) * 8192);
    const ushort4* s1 = (const ushort4*)(pe + ((size_t)b * 4 + 1) * 8192);
    const ushort4* s2 = (const ushort4*)(pe + ((size_t)b * 4 + 2) * 8192);
    const ushort4* s3 = (const ushort4*)(pe + ((size_t)b * 4 + 3) * 8192);
#pragma unroll
    for (int it = 0; it < 8; ++it) {
      int f = tid + it * 256;
      int row = f >> 5, d = (f & 31) * 4;
      ushort4 u0 = s0[f], u1 = s1[f], u2 = s2[f], u3 = s3[f];
      float sc = sLe[row];
      ushort4 o = { f2bf((bf2f(u0.x) + bf2f(u1.x) + bf2f(u2.x) + bf2f(u3.x)) * sc),
                    f2bf((bf2f(u0.y) + bf2f(u1.y) + bf2f(u2.y) + bf2f(u3.y)) * sc),
                    f2bf((bf2f(u0.z) + bf2f(u1.z) + bf2f(u2.z) + bf2f(u3.z)) * sc),
                    f2bf((bf2f(u0.w) + bf2f(u1.w) + bf2f(u2.w) + bf2f(u3.w)) * sc) };
      *(ushort4*)(sX + row * 136 + d) = o;
    }
  }
  __syncthreads();
  {
    short8 aF[4];
    const unsigned short* arow = sX + (w * 16 + m) * 136 + quad * 8;
#pragma unroll
    for (int c = 0; c < 4; ++c) aF[c] = *(const short8*)(arow + c * 32);
#pragma unroll
    for (int t = 0; t < 2; ++t) {
      int n = w * 32 + t * 16 + m;
      floatx4 acc = (floatx4){0.f, 0.f, 0.f, 0.f};
      const unsigned short* brow = wv_e + n * 128 + quad * 8;
#pragma unroll
      for (int c = 0; c < 4; ++c)
        acc = __builtin_amdgcn_mfma_f32_16x16x32_bf16(aF[c], *(const short8*)(brow + c * 32), acc, 0, 0, 0);
      float bb = bv_e[n];
#pragma unroll
      for (int r = 0; r < 4; ++r) sVH[(quad * 4 + r) * 136 + n] = f2bf(acc[r] + bb);
    }
  }
  __syncthreads();
  {
    short8 aF[4];
    const unsigned short* arow = sVH + m * 136 + quad * 8;
#pragma unroll
    for (int c = 0; c < 4; ++c) aF[c] = *(const short8*)(arow + c * 32);
#pragma unroll
    for (int t = 0; t < 2; ++t) {
      int n = w * 32 + t * 16 + m;
      floatx4 acc = (floatx4){0.f, 0.f, 0.f, 0.f};
      const unsigned short* brow = ow_e + n * 128 + quad * 8;
#pragma unroll
      for (int c = 0; c < 4; ++c)
        acc = __builtin_amdgcn_mfma_f32_16x16x32_bf16(aF[c], *(const short8*)(brow + c * 32), acc, 0, 0, 0);
      float bb = ob_e[n];
#pragma unroll
      for (int r = 0; r < 4; ++r) {
        int q = quad * 4 + r;
        sAcc[q * 132 + n] += acc[r] + bb;
      }
    }
  }
  __syncthreads();
  {
    int q = tid >> 4, li = tid & 15, d0 = li * 8;
    float x[8];
#pragma unroll
    for (int j = 0; j < 8; ++j) x[j] = sAcc[q * 132 + d0 + j];
    float s1 = 0.f, s2 = 0.f;
#pragma unroll
    for (int j = 0; j < 8; ++j) { s1 += x[j]; s2 += x[j] * x[j]; }
#pragma unroll
    for (int o = 1; o < 16; o <<= 1) { s1 += __shfl_xor(s1, o); s2 += __shfl_xor(s2, o); }
    float mean = s1 * (1.f / 128.f);
    float var = s2 * (1.f / 128.f) - mean * mean;
    float rstd = rsqrtf(var + 1e-5f);
    float y[8];
#pragma unroll
    for (int j = 0; j < 8; ++j)
      y[j] = (x[j] - mean) * rstd * ln2g[d0 + j] + ln2b[d0 + j];
    ushort4 o0 = { f2bf(y[0]), f2bf(y[1]), f2bf(y[2]), f2bf(y[3]) };
    ushort4 o1 = { f2bf(y[4]), f2bf(y[5]), f2bf(y[6]), f2bf(y[7]) };
    *(ushort4*)(sX + q * 136 + d0) = o0;
    *(ushort4*)(sX + q * 136 + d0 + 4) = o1;
  }
  __syncthreads();
  {
    short8 aF[4];
    const unsigned short* arow = sX + m * 136 + quad * 8;
#pragma unroll
    for (int c = 0; c < 4; ++c) aF[c] = *(const short8*)(arow + c * 32);
#pragma unroll
    for (int t = 0; t < 4; ++t) {
      int n = w * 64 + t * 16 + m;
      floatx4 acc = (floatx4){0.f, 0.f, 0.f, 0.f};
      const unsigned short* brow = w1 + n * 128 + quad * 8;
#pragma unroll
      for (int c = 0; c < 4; ++c)
        acc = __builtin_amdgcn_mfma_f32_16x16x32_bf16(aF[c], *(const short8*)(brow + c * 32), acc, 0, 0, 0);
      float bb = b1[n];
#pragma unroll
      for (int r = 0; r < 4; ++r)
        sF[(quad * 4 + r) * 264 + n] = f2bf(fmaxf(acc[r] + bb, 0.f));
    }
  }
  __syncthreads();
  {
    short8 aF[8];
    const unsigned short* arow = sF + m * 264 + quad * 8;
#pragma unroll
    for (int c = 0; c < 8; ++c) aF[c] = *(const short8*)(arow + c * 32);
#pragma unroll
    for (int t = 0; t < 2; ++t) {
      int n = w * 32 + t * 16 + m;
      floatx4 acc = (floatx4){0.f, 0.f, 0.f, 0.f};
      const unsigned short* brow = w2 + n * 256 + quad * 8;
#pragma unroll
      for (int c = 0; c < 8; ++c)
        acc = __builtin_amdgcn_mfma_f32_16x16x32_bf16(aF[c], *(const short8*)(brow + c * 32), acc, 0, 0, 0);
      float bb = b2[n];
#pragma unroll
      for (int r = 0; r < 4; ++r) {
        int q = quad * 4 + r;
        float fin = sAcc[q * 132 + n] + acc[r] + bb;
        lat[(size_t)b * 2048 + q * 128 + n] = fin;
        sAcc[q * 132 + n] = fin;
      }
    }
  }
  // ---- fused next-layer Q~ ----
  if (WtB_next) {
    __syncthreads();
    {
      int q = tid >> 4, li = tid & 15, d0 = li * 8;
      float x[8];
#pragma unroll
      for (int j = 0; j < 8; ++j) x[j] = sAcc[q * 132 + d0 + j];
      float s1 = 0.f, s2 = 0.f;
#pragma unroll
      for (int j = 0; j < 8; ++j) { s1 += x[j]; s2 += x[j] * x[j]; }
#pragma unroll
      for (int o = 1; o < 16; o <<= 1) { s1 += __shfl_xor(s1, o); s2 += __shfl_xor(s2, o); }
      float mean = s1 * (1.f / 128.f);
      float var = s2 * (1.f / 128.f) - mean * mean;
      float rstd = rsqrtf(var + 1e-5f);
      float y[8];
#pragma unroll
      for (int j = 0; j < 8; ++j)
        y[j] = (x[j] - mean) * rstd * lng1[d0 + j] + lnb1[d0 + j];
      ushort4 o0 = { f2bf(y[0]), f2bf(y[1]), f2bf(y[2]), f2bf(y[3]) };
      ushort4 o1 = { f2bf(y[4]), f2bf(y[5]), f2bf(y[6]), f2bf(y[7]) };
      *(ushort4*)(sX + q * 136 + d0) = o0;
      *(ushort4*)(sX + q * 136 + d0 + 4) = o1;
    }
    __syncthreads();
    short8 aF[4];
    const unsigned short* arow = sX + m * 136 + quad * 8;
#pragma unroll
    for (int c = 0; c < 4; ++c) aF[c] = *(const short8*)(arow + c * 32);
    unsigned short* qtb = Qt + (size_t)b * 16384;
#pragma unroll
    for (int t = 0; t < 16; ++t) {
      int tn = w * 16 + t;
      floatx4 acc = (floatx4){0.f, 0.f, 0.f, 0.f};
#pragma unroll
      for (int c = 0; c < 4; ++c) {
        short8 bF = *(const short8*)(WtB_next + (((size_t)tn * 4 + c) * 64 + lane) * 8);
        acc = __builtin_amdgcn_mfma_f32_16x16x32_bf16(aF[c], bF, acc, 0, 0, 0);
      }
      int n = tn * 16 + m;
      float bb = bt_next[n];
      int p = n >> 9, h = (n >> 7) & 3, d = n & 127;
      unsigned short* op = qtb + (p * 64 + h * 16) * 128 + d;
#pragma unroll
      for (int r = 0; r < 4; ++r) op[(quad * 4 + r) * 128] = f2bf(acc[r] + bb);
    }
  }
}

// ---------------- MFMA head: 16 batches per block, grid 32 ----------------
__global__ __launch_bounds__(256) void head_kernel(
    const float* __restrict__ lat, const unsigned short* __restrict__ w1b,
    const float* __restrict__ b1, const float* __restrict__ w2,
    const float* __restrict__ b2, float* __restrict__ out) {
  __shared__ __align__(16) unsigned short sA[16 * 2056];
  __shared__ float sW[4][16];
  const int tid = threadIdx.x;
  const int b0 = blockIdx.x * 16;
  for (int i = tid; i < 8192; i += 256) {
    int bb = i >> 9, c4 = i & 511;
    float4 v = ((const float4*)(lat + (size_t)(b0 + bb) * 2048))[c4];
    ushort4 u = { f2bf(v.x), f2bf(v.y), f2bf(v.z), f2bf(v.w) };
    *(ushort4*)(sA + bb * 2056 + c4 * 4) = u;
  }
  __syncthreads();
  const int lane = tid & 63, w = tid >> 6, m = lane & 15, quad = lane >> 4;
  float s[4] = {0.f, 0.f, 0.f, 0.f};
#pragma unroll
  for (int t = 0; t < 2; ++t) {
    int nt = w * 2 + t;
    int o = nt * 16 + m;
    floatx4 acc = (floatx4){0.f, 0.f, 0.f, 0.f};
    const unsigned short* brow = w1b + (size_t)o * 2048 + quad * 8;
    const unsigned short* arow = sA + m * 2056 + quad * 8;
    for (int c = 0; c < 64; ++c) {
      short8 aF = *(const short8*)(arow + c * 32);
      short8 bF = *(const short8*)(brow + c * 32);
      acc = __builtin_amdgcn_mfma_f32_16x16x32_bf16(aF, bF, acc, 0, 0, 0);
    }
    float w2v = w2[o];
    float b1v = b1[o];
#pragma unroll
    for (int r = 0; r < 4; ++r)
      s[r] += fmaxf(acc[r] + b1v, 0.f) * w2v;
  }
#pragma unroll
  for (int r = 0; r < 4; ++r) {
    float v = s[r];
    v += __shfl_xor(v, 1); v += __shfl_xor(v, 2);
    v += __shfl_xor(v, 4); v += __shfl_xor(v, 8);
    s[r] = v;
  }
  if (m == 0) {
#pragma unroll
    for (int r = 0; r < 4; ++r) sW[w][quad * 4 + r] = s[r];
  }
  __syncthreads();
  if (tid < 16) {
    float x = sW[0][tid] + sW[1][tid] + sW[2][tid] + sW[3][tid] + b2[0];
    out[b0 + tid] = (x > 20.f) ? x : log1pf(__expf(x));
  }
}

extern "C" void kernel_launch(void* const* d_in, const int* in_sizes, int n_in,
                              void* d_out, int out_size, void* d_ws, size_t ws_size,
                              hipStream_t stream) {
  const float* drug_k  = (const float*)d_in[0];
  const float* drug_v  = (const float*)d_in[1];
  const float* enz_k   = (const float*)d_in[2];
  const float* enz_v   = (const float*)d_in[3];
  const int*   drug_b  = (const int*)d_in[4];
  const int*   enz_b   = (const int*)d_in[5];
  const float* latents = (const float*)d_in[6];
  const float* wq_d    = (const float*)d_in[7];
  const float* bq_d    = (const float*)d_in[8];
  const float* wq_e    = (const float*)d_in[9];
  const float* bq_e    = (const float*)d_in[10];
  const float* mha_d_w = (const float*)d_in[11];
  const float* mha_d_b = (const float*)d_in[12];
  const float* mha_d_ow= (const float*)d_in[13];
  const float* mha_d_ob= (const float*)d_in[14];
  const float* mha_e_w = (const float*)d_in[15];
  const float* mha_e_b = (const float*)d_in[16];
  const float* mha_e_ow= (const float*)d_in[17];
  const float* mha_e_ob= (const float*)d_in[18];
  const float* ln1_g   = (const float*)d_in[19];
  const float* ln1_b   = (const float*)d_in[20];
  const float* ln2_g   = (const float*)d_in[21];
  const float* ln2_b   = (const float*)d_in[22];
  const float* ffn_w1  = (const float*)d_in[23];
  const float* ffn_b1  = (const float*)d_in[24];
  const float* ffn_w2  = (const float*)d_in[25];
  const float* ffn_b2  = (const float*)d_in[26];
  const float* head_w1 = (const float*)d_in[27];
  const float* head_b1 = (const float*)d_in[28];
  const float* head_w2 = (const float*)d_in[29];
  const float* head_b2 = (const float*)d_in[30];
  float* out = (float*)d_out;

  const int n_dk = in_sizes[0];   // 25600*128
  const int n_ek = in_sizes[2];   // 153600*128

  int* seg = (int*)d_ws;
  float* fws = (float*)d_ws;
  float* Wqf = fws + 2048;
  float* bqf = Wqf + 131072;
  float* lat = bqf + 1024;
  float* l_d = lat + 1048576;
  float* l_e = l_d + 32768;
  unsigned short* Qt     = (unsigned short*)(l_e + 131072);
  unsigned short* part_d = Qt + 8388608;
  unsigned short* part_e = part_d + 4194304;
  unsigned short* Kd_bf  = part_e + 16777216;
  unsigned short* Vd_bf  = Kd_bf + n_dk;
  unsigned short* Ke_bf  = Vd_bf + n_dk;
  unsigned short* Ve_bf  = Ke_bf + n_ek;
  unsigned short* Wbf    = Ve_bf + n_ek;            // 524288 ush
  unsigned short* WtB    = Wbf + 524288;            // 524288 ush
  float* bt              = (float*)(WtB + 524288);  // 4096 f
  unsigned short* w1h    = (unsigned short*)(bt + 4096);  // 262144 ush

  seg_kernel<<<2, 512, 0, stream>>>(drug_b, in_sizes[4], enz_b, in_sizes[5], seg);
  init_lat_kernel<<<1024, 256, 0, stream>>>(latents, lat);
  fold_kernel<<<64, 256, 0, stream>>>(wq_d, bq_d, wq_e, bq_e,
                                      mha_d_w, mha_d_b, mha_e_w, mha_e_b, Wqf, bqf);
  wt_kernel<<<32, 256, 0, stream>>>(Wqf, bqf, mha_d_w, mha_e_w, WtB, bt);
  cvtw_kernel<<<512, 256, 0, stream>>>(mha_d_w, mha_d_ow, mha_e_w, mha_e_ow,
                                       ffn_w1, ffn_w2, Wbf);
  cvth_kernel<<<256, 256, 0, stream>>>(head_w1, w1h);
  // layer-0 Q~ is batch-independent (lat == broadcast latents): grid 1, qstride 0
  qtilde_kernel<<<1, 256, 0, stream>>>(lat, ln1_g, ln1_b, WtB, bt, Qt);
  for (int l = 0; l < 4; ++l) {
    attn3_kernel<<<2560, 256, 0, stream>>>(drug_k, drug_v, enz_k, enz_v,
        Kd_bf, Vd_bf, Ke_bf, Ve_bf, seg,
        Qt, (l == 0) ? 0 : 16384, (l == 0) ? 1 : 0,
        part_d, l_d, part_e, l_e);
    const unsigned short* wtn = (l < 3) ? (WtB + (size_t)(l + 1) * 131072) : nullptr;
    const float* btn = (l < 3) ? (bt + (l + 1) * 1024) : nullptr;
    post_kernel<<<512, 256, 0, stream>>>(part_d, l_d, part_e, l_e,
        Wbf + (size_t)l * 131072,
        mha_d_b + l * 384 + 256, mha_d_ob + l * 128,
        mha_e_b + l * 384 + 256, mha_e_ob + l * 128,
        ln2_g + l * 128, ln2_b + l * 128,
        ffn_b1 + l * 256, ffn_b2 + l * 128,
        lat,
        ln1_g + (l + 1 < 4 ? (l + 1) * 128 : 0), ln1_b + (l + 1 < 4 ? (l + 1) * 128 : 0),
        wtn, btn, Qt);
  }
  head_kernel<<<32, 256, 0, stream>>>(lat, w1h, head_b1, head_w2, head_b2, out);
}